// Round 10
// baseline (984.313 us; speedup 1.0000x reference)
//
#include <hip/hip_runtime.h>
#include <stdint.h>

#define B_DIM 16384
#define V_DIM 1024
#define H_DIM 256
#define K_STEPS 8

typedef short bf16x8 __attribute__((ext_vector_type(8)));
typedef float f32x4 __attribute__((ext_vector_type(4)));

// ---------------- Threefry-2x32-20, bit-exact JAX replica ----------------
__host__ __device__ inline uint32_t rotl32(uint32_t v, int r) {
#if defined(__HIP_DEVICE_COMPILE__)
    return __builtin_amdgcn_alignbit(v, v, (uint32_t)(32 - r));
#else
    return (v << r) | (v >> (32 - r));
#endif
}

__host__ __device__ inline void threefry2x32(uint32_t k0, uint32_t k1,
                                             uint32_t x0, uint32_t x1,
                                             uint32_t* o0, uint32_t* o1) {
    uint32_t k2 = k0 ^ k1 ^ 0x1BD11BDAu;
    x0 += k0; x1 += k1;
#define TF_RND(r) { x0 += x1; x1 = rotl32(x1, (r)); x1 ^= x0; }
    TF_RND(13) TF_RND(15) TF_RND(26) TF_RND(6)
    x0 += k1; x1 += k2 + 1u;
    TF_RND(17) TF_RND(29) TF_RND(16) TF_RND(24)
    x0 += k2; x1 += k0 + 2u;
    TF_RND(13) TF_RND(15) TF_RND(26) TF_RND(6)
    x0 += k0; x1 += k1 + 3u;
    TF_RND(17) TF_RND(29) TF_RND(16) TF_RND(24)
    x0 += k1; x1 += k2 + 4u;
    TF_RND(13) TF_RND(15) TF_RND(26) TF_RND(6)
    x0 += k2; x1 += k0 + 5u;
#undef TF_RND
    *o0 = x0; *o1 = x1;
}

// Partitionable-threefry uniform (bits = o0 ^ o1 of counter (0, e)).
__device__ inline float tf_uniform(uint32_t key0, uint32_t key1, uint32_t e) {
    uint32_t o0, o1;
    threefry2x32(key0, key1, 0u, e, &o0, &o1);
    uint32_t bits = o0 ^ o1;
    return __uint_as_float((bits >> 9) | 0x3f800000u) - 1.0f;
}

__device__ inline uint16_t bf16_rn(float f) {
    uint32_t u = __float_as_uint(f);
    uint32_t r = u + 0x7FFFu + ((u >> 16) & 1u);
    return (uint16_t)(r >> 16);
}
__device__ inline float bf16_to_f32(uint16_t h) {
    return __uint_as_float(((uint32_t)h) << 16);
}

__device__ inline void gload_lds16(const void* g, void* l) {
    __builtin_amdgcn_global_load_lds((const __attribute__((address_space(1))) uint32_t*)g,
                                     (__attribute__((address_space(3))) uint32_t*)l, 16, 0, 0);
}

// ---------------- LDS MFMA NT-GEMM, 64x128 tile, BK=32 ----------------
// C[M x N] = A[M x K] * Bt[N x K]^T (+ bias). 4 waves 2x2, each 32x64 (2x4 frags).
// 16 MFMA per wave per 32-k (2x density of the 64x64 tile); A-traffic halved
// (grid_y = N/128). Per-accumulator MFMA order (hi then lo, k ascending)
// identical to prior rounds -> bit-identical h sample stream.
// MODE 0: split-B, threefry sample via fma-compare -> bf16 {0,1}
// MODE 1: split-B, sigmoid -> bf16 probs (precise divide, stored)
// MODE 3: split-B, sample (fma-compare) -> out AND probs (divide) -> out2
template <int MODE>
__global__ __launch_bounds__(256, 6) void mfma_gemm(
    const ushort* __restrict__ A, const ushort* __restrict__ Bhi,
    const ushort* __restrict__ Blo, const float* __restrict__ bias,
    ushort* __restrict__ out, ushort* __restrict__ out2,
    int N, int K, uint32_t key0, uint32_t key1) {
    __shared__ __align__(16) ushort As[64 * 32];    // 4 KB
    __shared__ __align__(16) ushort Bs[128 * 32];   // 8 KB
    __shared__ __align__(16) ushort Bs2[128 * 32];  // 8 KB

    const int tid = threadIdx.x;
    const int lane = tid & 63;
    const int w = tid >> 6;
    const int m0 = blockIdx.x * 64;
    const int n0 = blockIdx.y * 128;

    f32x4 acc[2][4] = {};

    const int wm = (w & 1) * 32;
    const int wn = (w >> 1) * 64;
    const int q = lane >> 4;
    const int l15 = lane & 15;
    const int srow = lane >> 2;       // 0..15
    const int scol = (lane & 3) * 8;  // 0,8,16,24

    // A: wave w stages rows [16w, 16w+16) of the 64-row tile (1 gload)
    const size_t arow = (size_t)(m0 + w * 16 + srow) * K;
    // B: wave w stages rows [32w, 32w+32) of the 128-row tile (2 gloads/split)
    const size_t brow0 = (size_t)(n0 + w * 32 + srow) * K;
    const size_t brow1 = brow0 + 16 * K;

    for (int k0 = 0; k0 < K; k0 += 32) {
        gload_lds16(&A[arow + k0 + scol], &As[w * 512]);
        gload_lds16(&Bhi[brow0 + k0 + scol], &Bs[w * 1024]);
        gload_lds16(&Bhi[brow1 + k0 + scol], &Bs[w * 1024 + 512]);
        gload_lds16(&Blo[brow0 + k0 + scol], &Bs2[w * 1024]);
        gload_lds16(&Blo[brow1 + k0 + scol], &Bs2[w * 1024 + 512]);
        __syncthreads();
        bf16x8 af[2];
#pragma unroll
        for (int i = 0; i < 2; ++i)
            af[i] = *(const bf16x8*)&As[(wm + i * 16 + l15) * 32 + q * 8];
#pragma unroll
        for (int j = 0; j < 4; ++j) {
            bf16x8 bh = *(const bf16x8*)&Bs[(wn + j * 16 + l15) * 32 + q * 8];
            bf16x8 bl = *(const bf16x8*)&Bs2[(wn + j * 16 + l15) * 32 + q * 8];
#pragma unroll
            for (int i = 0; i < 2; ++i) {
                acc[i][j] = __builtin_amdgcn_mfma_f32_16x16x32_bf16(af[i], bh, acc[i][j], 0, 0, 0);
                acc[i][j] = __builtin_amdgcn_mfma_f32_16x16x32_bf16(af[i], bl, acc[i][j], 0, 0, 0);
            }
        }
        __syncthreads();
    }

    const int orow = q * 4;
#pragma unroll
    for (int i = 0; i < 2; ++i) {
#pragma unroll
        for (int j = 0; j < 4; ++j) {
            int col = n0 + wn + j * 16 + l15;
            float bv = bias[col];
#pragma unroll
            for (int r = 0; r < 4; ++r) {
                int row = m0 + wm + i * 16 + orow + r;
                float val = acc[i][j][r] + bv;
                if (MODE == 0) {
                    float E = expf(-val);
                    uint32_t e = (uint32_t)row * (uint32_t)N + (uint32_t)col;
                    float u = tf_uniform(key0, key1, e);
                    out[(size_t)row * N + col] = (fmaf(u, E, u) < 1.0f) ? (ushort)0x3F80 : (ushort)0;
                } else if (MODE == 3) {
                    float E = expf(-val);
                    float sg = 1.0f / (1.0f + E);
                    uint32_t e = (uint32_t)row * (uint32_t)N + (uint32_t)col;
                    float u = tf_uniform(key0, key1, e);
                    out[(size_t)row * N + col] = (fmaf(u, E, u) < 1.0f) ? (ushort)0x3F80 : (ushort)0;
                    out2[(size_t)row * N + col] = bf16_rn(sg);
                } else {
                    float sg = 1.0f / (1.0f + expf(-val));
                    out[(size_t)row * N + col] = bf16_rn(sg);
                }
            }
        }
    }
}

// ---------------- Sparse v-side sampler (round-8 proven form) ----------------
__global__ __launch_bounds__(256, 8) void vsample_kernel(
    const ushort* __restrict__ h,   // [B,256] bf16 {0,1}
    const float* __restrict__ W,    // [256,1024] fp32 (native layout)
    const float* __restrict__ vb,   // [1024]
    ushort* __restrict__ vout,      // [B,1024] bf16 {0,1}
    uint32_t key0, uint32_t key1) {
    const int lane = threadIdx.x & 63;
    const int wid = threadIdx.x >> 6;

    float vbr[16];
#pragma unroll
    for (int t = 0; t < 16; ++t) vbr[t] = vb[lane + 64 * t];

    const int row_base = blockIdx.x * 8 + wid * 2;
#pragma unroll
    for (int rr = 0; rr < 2; ++rr) {
        const int b = row_base + rr;
        ushort4 hv = ((const ushort4*)(h + (size_t)b * H_DIM))[lane];
        unsigned long long masks[4];
        masks[0] = __ballot(hv.x != 0);
        masks[1] = __ballot(hv.y != 0);
        masks[2] = __ballot(hv.z != 0);
        masks[3] = __ballot(hv.w != 0);

        float acc[16];
#pragma unroll
        for (int t = 0; t < 16; ++t) acc[t] = 0.0f;

#pragma unroll
        for (int s = 0; s < 4; ++s) {
            unsigned long long m = masks[s];
            while (m) {  // wave-uniform loop, no divergence
                int l = __ffsll(m) - 1;
                m &= m - 1;
                int j = l * 4 + s;
                const float* wrow = W + (size_t)j * V_DIM + lane;
#pragma unroll
                for (int t = 0; t < 16; ++t) acc[t] += wrow[64 * t];
            }
        }

        const uint32_t ebase = (uint32_t)b * (uint32_t)V_DIM + (uint32_t)lane;
        ushort* orow = vout + (size_t)b * V_DIM + lane;
#pragma unroll
        for (int t = 0; t < 16; ++t) {
            float pre = acc[t] + vbr[t];
            float sg = 1.0f / (1.0f + expf(-pre));
            float u = tf_uniform(key0, key1, ebase + 64u * (uint32_t)t);
            orow[64 * t] = (u < sg) ? (ushort)0x3F80 : (ushort)0;
        }
    }
}

// ---------------- LDS MFMA NT-GEMM accumulate (gw) ----------------
__global__ __launch_bounds__(256, 4) void mfma_gemm_acc(
    const ushort* __restrict__ A, const ushort* __restrict__ Bt,
    float* __restrict__ out, int N, int K, int k_slice) {
    __shared__ __align__(16) ushort As[64 * 32];
    __shared__ __align__(16) ushort Bs[64 * 32];

    const int tid = threadIdx.x;
    const int lane = tid & 63;
    const int w = tid >> 6;
    const int m0 = blockIdx.x * 64;
    const int n0 = blockIdx.y * 64;
    const int kbase = blockIdx.z * k_slice;

    f32x4 acc[2][2] = {};

    const int wm = (w & 1) * 32;
    const int wn = (w >> 1) * 32;
    const int q = lane >> 4;
    const int l15 = lane & 15;
    const int srow = lane >> 2;
    const int scol = (lane & 3) * 8;

    const size_t arow = (size_t)(m0 + w * 16 + srow) * K;
    const size_t brow = (size_t)(n0 + w * 16 + srow) * K;

    for (int kt = 0; kt < k_slice; kt += 32) {
        const int k0 = kbase + kt;
        gload_lds16(&A[arow + k0 + scol], &As[w * 512]);
        gload_lds16(&Bt[brow + k0 + scol], &Bs[w * 512]);
        __syncthreads();
        bf16x8 af[2], bf[2];
#pragma unroll
        for (int i = 0; i < 2; ++i) {
            af[i] = *(const bf16x8*)&As[(wm + i * 16 + l15) * 32 + q * 8];
            bf[i] = *(const bf16x8*)&Bs[(wn + i * 16 + l15) * 32 + q * 8];
        }
#pragma unroll
        for (int i = 0; i < 2; ++i)
#pragma unroll
            for (int j = 0; j < 2; ++j)
                acc[i][j] = __builtin_amdgcn_mfma_f32_16x16x32_bf16(af[i], bf[j], acc[i][j], 0, 0, 0);
        __syncthreads();
    }

    const int orow = q * 4;
#pragma unroll
    for (int i = 0; i < 2; ++i)
#pragma unroll
        for (int j = 0; j < 2; ++j) {
            int col = n0 + wn + j * 16 + l15;
#pragma unroll
            for (int r = 0; r < 4; ++r) {
                int row = m0 + wm + i * 16 + orow + r;
                atomicAdd(&out[(size_t)row * N + col], acc[i][j][r]);
            }
        }
}

// ---------------- W split into bf16 hi/lo ----------------
__global__ void wsplit_kernel(const float* __restrict__ W, ushort* __restrict__ whi,
                              ushort* __restrict__ wlo) {
    int idx = blockIdx.x * 256 + threadIdx.x;
    float w = W[idx];
    ushort hi = bf16_rn(w);
    float fhi = bf16_to_f32(hi);
    ushort lo = bf16_rn(w - fhi);
    whi[idx] = hi; wlo[idx] = lo;
}

__global__ void tobf16_kernel(const float* __restrict__ src, ushort* __restrict__ dst) {
    int idx = blockIdx.x * 256 + threadIdx.x;
    float4 f = ((const float4*)src)[idx];
    ushort4 o;
    o.x = bf16_rn(f.x); o.y = bf16_rn(f.y); o.z = bf16_rn(f.z); o.w = bf16_rn(f.w);
    ((ushort4*)dst)[idx] = o;
}

// ---------------- log-norm ----------------
__global__ __launch_bounds__(256) void lognorm_kernel(
    const ushort* __restrict__ phk, const ushort* __restrict__ vk,
    const float* __restrict__ vb, float* __restrict__ inv) {
    int b = blockIdx.x;
    int tid = threadIdx.x;
    float p = bf16_to_f32(phk[(size_t)b * H_DIM + tid]);
    float s = -log1pf(-p);
    for (int j = tid; j < V_DIM; j += 256)
        s += bf16_to_f32(vk[(size_t)b * V_DIM + j]) * vb[j];
    for (int off = 32; off > 0; off >>= 1) s += __shfl_down(s, off, 64);
    __shared__ float wsum[4];
    int lane = tid & 63, wid = tid >> 6;
    if (lane == 0) wsum[wid] = s;
    __syncthreads();
    if (tid == 0) {
        float t = wsum[0] + wsum[1] + wsum[2] + wsum[3];
        inv[b] = expf(-t) * (1.0f / 16384.0f);
    }
}

// ---------------- transposes for gw GEMM ----------------
__global__ void build_At(const ushort* __restrict__ P, const float* __restrict__ inv,
                         float sgn, ushort* __restrict__ At) {
    __shared__ float T[64][65];
    int c = threadIdx.x & 63;
    int rb = threadIdx.x >> 6;
    int b0 = blockIdx.x * 64;
    int h0 = blockIdx.y * 64;
    for (int r = rb; r < 64; r += 4) {
        int b = b0 + r;
        T[c][r] = sgn * inv[b] * bf16_to_f32(P[(size_t)b * H_DIM + h0 + c]);
    }
    __syncthreads();
    for (int r = rb; r < 64; r += 4)
        At[(size_t)(h0 + r) * B_DIM + b0 + c] = bf16_rn(T[r][c]);
}

__global__ void build_Bt(const ushort* __restrict__ Sb, const float* __restrict__ Sf,
                         int use_f32, ushort* __restrict__ Bt) {
    __shared__ ushort T[64][65];
    int c = threadIdx.x & 63;
    int rb = threadIdx.x >> 6;
    int b0 = blockIdx.x * 64;
    int v0 = blockIdx.y * 64;
    for (int r = rb; r < 64; r += 4) {
        int b = b0 + r;
        T[c][r] = use_f32 ? bf16_rn(Sf[(size_t)b * V_DIM + v0 + c])
                          : Sb[(size_t)b * V_DIM + v0 + c];
    }
    __syncthreads();
    for (int r = rb; r < 64; r += 4)
        Bt[(size_t)(v0 + r) * B_DIM + b0 + c] = T[r][c];
}

// ---------------- g_vb / g_hb ----------------
__global__ void gvb_kernel(const ushort* __restrict__ vk, const ushort* __restrict__ vbat,
                           const float* __restrict__ inv, float* __restrict__ gvb) {
    int col = blockIdx.x * 256 + threadIdx.x;
    int b0 = blockIdx.y * 512;
    float acc = 0.0f;
    for (int r = 0; r < 512; ++r) {
        int b = b0 + r;
        acc += inv[b] * (bf16_to_f32(vk[(size_t)b * V_DIM + col]) -
                         bf16_to_f32(vbat[(size_t)b * V_DIM + col]));
    }
    atomicAdd(&gvb[col], acc);
}

__global__ void ghb_kernel(const ushort* __restrict__ phk, const ushort* __restrict__ ph0,
                           const float* __restrict__ inv, float* __restrict__ ghb) {
    int col = threadIdx.x;
    int b0 = blockIdx.x * 256;
    float acc = 0.0f;
    for (int r = 0; r < 256; ++r) {
        int b = b0 + r;
        acc += inv[b] * (bf16_to_f32(phk[(size_t)b * H_DIM + col]) -
                         bf16_to_f32(ph0[(size_t)b * H_DIM + col]));
    }
    atomicAdd(&ghb[col], acc);
}

extern "C" void kernel_launch(void* const* d_in, const int* in_sizes, int n_in,
                              void* d_out, int out_size, void* d_ws, size_t ws_size,
                              hipStream_t stream) {
    const float* batch = (const float*)d_in[0];
    const float* W = (const float*)d_in[1];
    const float* vb = (const float*)d_in[2];
    const float* hb = (const float*)d_in[3];

    char* base = (char*)d_ws;
    ushort* w_hi  = (ushort*)(base + 0);          // 512 KB
    ushort* w_lo  = (ushort*)(base + 524288);
    ushort* v_cur = (ushort*)(base + 2097152);    // 32 MB
    float*  inv   = (float*)(base + 35651584);    // 64 KB
    ushort* h_cur = (ushort*)(base + 35717120);   // 8 MB (aliased: At after loop)
    ushort* At    = h_cur;
    ushort* batch_bf = (ushort*)(base + 44105728); // 32 MB (aliased: Bt after last use)
    ushort* Bt    = batch_bf;
    ushort* ph0b  = (ushort*)(base + 77660160);   // 8 MB
    ushort* phkb  = (ushort*)(base + 86048768);   // 8 MB -> total 94437376 B

    float* gw  = (float*)d_out;
    float* gvb = gw + (size_t)H_DIM * V_DIM;
    float* ghb = gvb + V_DIM;

    hipMemsetAsync(d_out, 0, (size_t)out_size * sizeof(float), stream);

    // Partitionable threefry split of key(42): subkey[n] = threefry((0,42),(0,n)).
    uint32_t sk0[16], sk1[16];
    for (int n = 0; n < 16; ++n) threefry2x32(0u, 42u, 0u, (uint32_t)n, &sk0[n], &sk1[n]);

    wsplit_kernel<<<dim3(1024), dim3(256), 0, stream>>>(W, w_hi, w_lo);
    tobf16_kernel<<<dim3(B_DIM * V_DIM / 4 / 256), dim3(256), 0, stream>>>(batch, batch_bf);

    for (int i = 0; i < K_STEPS; ++i) {
        const ushort* vin = (i == 0) ? batch_bf : v_cur;
        if (i == 0) {
            mfma_gemm<3><<<dim3(B_DIM / 64, H_DIM / 128), dim3(256), 0, stream>>>(
                vin, w_hi, w_lo, hb, h_cur, ph0b, H_DIM, V_DIM, sk0[0], sk1[0]);
        } else {
            mfma_gemm<0><<<dim3(B_DIM / 64, H_DIM / 128), dim3(256), 0, stream>>>(
                vin, w_hi, w_lo, hb, h_cur, nullptr, H_DIM, V_DIM, sk0[2 * i], sk1[2 * i]);
        }
        vsample_kernel<<<dim3(B_DIM / 8), dim3(256), 0, stream>>>(
            h_cur, W, vb, v_cur, sk0[2 * i + 1], sk1[2 * i + 1]);
    }
    // negative phase hidden probs from vk
    mfma_gemm<1><<<dim3(B_DIM / 64, H_DIM / 128), dim3(256), 0, stream>>>(
        v_cur, w_hi, w_lo, hb, phkb, nullptr, H_DIM, V_DIM, 0u, 0u);

    lognorm_kernel<<<dim3(B_DIM), dim3(256), 0, stream>>>(phkb, v_cur, vb, inv);
    ghb_kernel<<<dim3(B_DIM / 256), dim3(256), 0, stream>>>(phkb, ph0b, inv, ghb);
    gvb_kernel<<<dim3(V_DIM / 256, B_DIM / 512), dim3(256), 0, stream>>>(v_cur, batch_bf, inv, gvb);

    // g_W positive phase
    build_At<<<dim3(B_DIM / 64, H_DIM / 64), dim3(256), 0, stream>>>(phkb, inv, 1.0f, At);
    build_Bt<<<dim3(B_DIM / 64, V_DIM / 64), dim3(256), 0, stream>>>(v_cur, nullptr, 0, Bt);
    mfma_gemm_acc<<<dim3(H_DIM / 64, V_DIM / 64, 16), dim3(256), 0, stream>>>(
        At, Bt, gw, V_DIM, B_DIM, 1024);
    // g_W negative phase
    build_At<<<dim3(B_DIM / 64, H_DIM / 64), dim3(256), 0, stream>>>(ph0b, inv, -1.0f, At);
    build_Bt<<<dim3(B_DIM / 64, V_DIM / 64), dim3(256), 0, stream>>>(nullptr, batch, 1, Bt);
    mfma_gemm_acc<<<dim3(H_DIM / 64, V_DIM / 64, 16), dim3(256), 0, stream>>>(
        At, Bt, gw, V_DIM, B_DIM, 1024);
}

// Round 11
// 905.380 us; speedup vs baseline: 1.0872x; 1.0872x over previous
//
#include <hip/hip_runtime.h>
#include <stdint.h>

#define B_DIM 16384
#define V_DIM 1024
#define H_DIM 256
#define K_STEPS 8

typedef short bf16x8 __attribute__((ext_vector_type(8)));
typedef float f32x4 __attribute__((ext_vector_type(4)));

// ---------------- Threefry-2x32-20, bit-exact JAX replica ----------------
__host__ __device__ inline uint32_t rotl32(uint32_t v, int r) {
#if defined(__HIP_DEVICE_COMPILE__)
    return __builtin_amdgcn_alignbit(v, v, (uint32_t)(32 - r));
#else
    return (v << r) | (v >> (32 - r));
#endif
}

__host__ __device__ inline void threefry2x32(uint32_t k0, uint32_t k1,
                                             uint32_t x0, uint32_t x1,
                                             uint32_t* o0, uint32_t* o1) {
    uint32_t k2 = k0 ^ k1 ^ 0x1BD11BDAu;
    x0 += k0; x1 += k1;
#define TF_RND(r) { x0 += x1; x1 = rotl32(x1, (r)); x1 ^= x0; }
    TF_RND(13) TF_RND(15) TF_RND(26) TF_RND(6)
    x0 += k1; x1 += k2 + 1u;
    TF_RND(17) TF_RND(29) TF_RND(16) TF_RND(24)
    x0 += k2; x1 += k0 + 2u;
    TF_RND(13) TF_RND(15) TF_RND(26) TF_RND(6)
    x0 += k0; x1 += k1 + 3u;
    TF_RND(17) TF_RND(29) TF_RND(16) TF_RND(24)
    x0 += k1; x1 += k2 + 4u;
    TF_RND(13) TF_RND(15) TF_RND(26) TF_RND(6)
    x0 += k2; x1 += k0 + 5u;
#undef TF_RND
    *o0 = x0; *o1 = x1;
}

// Partitionable-threefry uniform (bits = o0 ^ o1 of counter (0, e)).
__device__ inline float tf_uniform(uint32_t key0, uint32_t key1, uint32_t e) {
    uint32_t o0, o1;
    threefry2x32(key0, key1, 0u, e, &o0, &o1);
    uint32_t bits = o0 ^ o1;
    return __uint_as_float((bits >> 9) | 0x3f800000u) - 1.0f;
}

__device__ inline uint16_t bf16_rn(float f) {
    uint32_t u = __float_as_uint(f);
    uint32_t r = u + 0x7FFFu + ((u >> 16) & 1u);
    return (uint16_t)(r >> 16);
}
__device__ inline float bf16_to_f32(uint16_t h) {
    return __uint_as_float(((uint32_t)h) << 16);
}

__device__ inline void gload_lds16(const void* g, void* l) {
    __builtin_amdgcn_global_load_lds((const __attribute__((address_space(1))) uint32_t*)g,
                                     (__attribute__((address_space(3))) uint32_t*)l, 16, 0, 0);
}

// ---------------- LDS MFMA NT-GEMM, 64x64 tile, BK=64 (round-8 proven) ----------------
// C[M x N] = A[M x K] * Bt[N x K]^T (+ bias). 4 waves, each 32x32 (2x2 frags).
// grid_y = N/64 keeps >=4 blocks/CU (r10 showed 64x128 tile -> 2/CU regresses).
// MODE 0: split-B, threefry sample via fma-compare -> bf16 {0,1}
//         (u < 1/(1+E) <=> fma(u,E,u) < 1; zero flips observed in 6.7e7 draws r9/r10)
// MODE 1: split-B, sigmoid -> bf16 probs (precise divide, stored)
// MODE 3: split-B, sample (fma-compare) -> out AND probs (divide) -> out2
template <int MODE>
__global__ __launch_bounds__(256, 4) void mfma_gemm(
    const ushort* __restrict__ A, const ushort* __restrict__ Bhi,
    const ushort* __restrict__ Blo, const float* __restrict__ bias,
    ushort* __restrict__ out, ushort* __restrict__ out2,
    int N, int K, uint32_t key0, uint32_t key1) {
    __shared__ __align__(16) ushort As[2][64 * 32];
    __shared__ __align__(16) ushort Bs[2][64 * 32];
    __shared__ __align__(16) ushort Bs2[2][64 * 32];

    const int tid = threadIdx.x;
    const int lane = tid & 63;
    const int w = tid >> 6;
    const int m0 = blockIdx.x * 64;
    const int n0 = blockIdx.y * 64;

    f32x4 acc[2][2] = {};

    const int wm = (w & 1) * 32;
    const int wn = (w >> 1) * 32;
    const int q = lane >> 4;
    const int l15 = lane & 15;
    const int srow = lane >> 2;
    const int scol = (lane & 3) * 8;

    const size_t arow = (size_t)(m0 + w * 16 + srow) * K;
    const size_t brow = (size_t)(n0 + w * 16 + srow) * K;

    for (int k0 = 0; k0 < K; k0 += 64) {
#pragma unroll
        for (int s = 0; s < 2; ++s) {
            gload_lds16(&A[arow + k0 + s * 32 + scol], &As[s][w * 512]);
            gload_lds16(&Bhi[brow + k0 + s * 32 + scol], &Bs[s][w * 512]);
            gload_lds16(&Blo[brow + k0 + s * 32 + scol], &Bs2[s][w * 512]);
        }
        __syncthreads();
#pragma unroll
        for (int s = 0; s < 2; ++s) {
            bf16x8 af[2], bh[2], bl[2];
#pragma unroll
            for (int i = 0; i < 2; ++i)
                af[i] = *(const bf16x8*)&As[s][(wm + i * 16 + l15) * 32 + q * 8];
#pragma unroll
            for (int j = 0; j < 2; ++j) {
                bh[j] = *(const bf16x8*)&Bs[s][(wn + j * 16 + l15) * 32 + q * 8];
                bl[j] = *(const bf16x8*)&Bs2[s][(wn + j * 16 + l15) * 32 + q * 8];
            }
#pragma unroll
            for (int i = 0; i < 2; ++i)
#pragma unroll
                for (int j = 0; j < 2; ++j) {
                    acc[i][j] = __builtin_amdgcn_mfma_f32_16x16x32_bf16(af[i], bh[j], acc[i][j], 0, 0, 0);
                    acc[i][j] = __builtin_amdgcn_mfma_f32_16x16x32_bf16(af[i], bl[j], acc[i][j], 0, 0, 0);
                }
        }
        __syncthreads();
    }

    const int orow = q * 4;
#pragma unroll
    for (int i = 0; i < 2; ++i) {
#pragma unroll
        for (int j = 0; j < 2; ++j) {
            int col = n0 + wn + j * 16 + l15;
            float bv = bias[col];
#pragma unroll
            for (int r = 0; r < 4; ++r) {
                int row = m0 + wm + i * 16 + orow + r;
                float val = acc[i][j][r] + bv;
                if (MODE == 0) {
                    float E = expf(-val);
                    uint32_t e = (uint32_t)row * (uint32_t)N + (uint32_t)col;
                    float u = tf_uniform(key0, key1, e);
                    out[(size_t)row * N + col] = (fmaf(u, E, u) < 1.0f) ? (ushort)0x3F80 : (ushort)0;
                } else if (MODE == 3) {
                    float E = expf(-val);
                    float sg = 1.0f / (1.0f + E);
                    uint32_t e = (uint32_t)row * (uint32_t)N + (uint32_t)col;
                    float u = tf_uniform(key0, key1, e);
                    out[(size_t)row * N + col] = (fmaf(u, E, u) < 1.0f) ? (ushort)0x3F80 : (ushort)0;
                    out2[(size_t)row * N + col] = bf16_rn(sg);
                } else {
                    float sg = 1.0f / (1.0f + expf(-val));
                    out[(size_t)row * N + col] = bf16_rn(sg);
                }
            }
        }
    }
}

// ---------------- Sparse v-side sampler (round-8 proven body, fma-compare) ----------------
__global__ __launch_bounds__(256, 8) void vsample_kernel(
    const ushort* __restrict__ h,   // [B,256] bf16 {0,1}
    const float* __restrict__ W,    // [256,1024] fp32 (native layout)
    const float* __restrict__ vb,   // [1024]
    ushort* __restrict__ vout,      // [B,1024] bf16 {0,1}
    uint32_t key0, uint32_t key1) {
    const int lane = threadIdx.x & 63;
    const int wid = threadIdx.x >> 6;

    float vbr[16];
#pragma unroll
    for (int t = 0; t < 16; ++t) vbr[t] = vb[lane + 64 * t];

    const int row_base = blockIdx.x * 8 + wid * 2;
#pragma unroll
    for (int rr = 0; rr < 2; ++rr) {
        const int b = row_base + rr;
        ushort4 hv = ((const ushort4*)(h + (size_t)b * H_DIM))[lane];
        unsigned long long masks[4];
        masks[0] = __ballot(hv.x != 0);
        masks[1] = __ballot(hv.y != 0);
        masks[2] = __ballot(hv.z != 0);
        masks[3] = __ballot(hv.w != 0);

        float acc[16];
#pragma unroll
        for (int t = 0; t < 16; ++t) acc[t] = 0.0f;

#pragma unroll
        for (int s = 0; s < 4; ++s) {
            unsigned long long m = masks[s];
            while (m) {  // wave-uniform loop, no divergence
                int l = __ffsll(m) - 1;
                m &= m - 1;
                int j = l * 4 + s;
                const float* wrow = W + (size_t)j * V_DIM + lane;
#pragma unroll
                for (int t = 0; t < 16; ++t) acc[t] += wrow[64 * t];
            }
        }

        const uint32_t ebase = (uint32_t)b * (uint32_t)V_DIM + (uint32_t)lane;
        ushort* orow = vout + (size_t)b * V_DIM + lane;
#pragma unroll
        for (int t = 0; t < 16; ++t) {
            float pre = acc[t] + vbr[t];
            float E = expf(-pre);
            float u = tf_uniform(key0, key1, ebase + 64u * (uint32_t)t);
            orow[64 * t] = (fmaf(u, E, u) < 1.0f) ? (ushort)0x3F80 : (ushort)0;
        }
    }
}

// ---------------- LDS MFMA NT-GEMM accumulate (gw) ----------------
__global__ __launch_bounds__(256, 4) void mfma_gemm_acc(
    const ushort* __restrict__ A, const ushort* __restrict__ Bt,
    float* __restrict__ out, int N, int K, int k_slice) {
    __shared__ __align__(16) ushort As[64 * 32];
    __shared__ __align__(16) ushort Bs[64 * 32];

    const int tid = threadIdx.x;
    const int lane = tid & 63;
    const int w = tid >> 6;
    const int m0 = blockIdx.x * 64;
    const int n0 = blockIdx.y * 64;
    const int kbase = blockIdx.z * k_slice;

    f32x4 acc[2][2] = {};

    const int wm = (w & 1) * 32;
    const int wn = (w >> 1) * 32;
    const int q = lane >> 4;
    const int l15 = lane & 15;
    const int srow = lane >> 2;
    const int scol = (lane & 3) * 8;

    const size_t arow = (size_t)(m0 + w * 16 + srow) * K;
    const size_t brow = (size_t)(n0 + w * 16 + srow) * K;

    for (int kt = 0; kt < k_slice; kt += 32) {
        const int k0 = kbase + kt;
        gload_lds16(&A[arow + k0 + scol], &As[w * 512]);
        gload_lds16(&Bt[brow + k0 + scol], &Bs[w * 512]);
        __syncthreads();
        bf16x8 af[2], bf[2];
#pragma unroll
        for (int i = 0; i < 2; ++i) {
            af[i] = *(const bf16x8*)&As[(wm + i * 16 + l15) * 32 + q * 8];
            bf[i] = *(const bf16x8*)&Bs[(wn + i * 16 + l15) * 32 + q * 8];
        }
#pragma unroll
        for (int i = 0; i < 2; ++i)
#pragma unroll
            for (int j = 0; j < 2; ++j)
                acc[i][j] = __builtin_amdgcn_mfma_f32_16x16x32_bf16(af[i], bf[j], acc[i][j], 0, 0, 0);
        __syncthreads();
    }

    const int orow = q * 4;
#pragma unroll
    for (int i = 0; i < 2; ++i)
#pragma unroll
        for (int j = 0; j < 2; ++j) {
            int col = n0 + wn + j * 16 + l15;
#pragma unroll
            for (int r = 0; r < 4; ++r) {
                int row = m0 + wm + i * 16 + orow + r;
                atomicAdd(&out[(size_t)row * N + col], acc[i][j][r]);
            }
        }
}

// ---------------- W split into bf16 hi/lo ----------------
__global__ void wsplit_kernel(const float* __restrict__ W, ushort* __restrict__ whi,
                              ushort* __restrict__ wlo) {
    int idx = blockIdx.x * 256 + threadIdx.x;
    float w = W[idx];
    ushort hi = bf16_rn(w);
    float fhi = bf16_to_f32(hi);
    ushort lo = bf16_rn(w - fhi);
    whi[idx] = hi; wlo[idx] = lo;
}

__global__ void tobf16_kernel(const float* __restrict__ src, ushort* __restrict__ dst) {
    int idx = blockIdx.x * 256 + threadIdx.x;
    float4 f = ((const float4*)src)[idx];
    ushort4 o;
    o.x = bf16_rn(f.x); o.y = bf16_rn(f.y); o.z = bf16_rn(f.z); o.w = bf16_rn(f.w);
    ((ushort4*)dst)[idx] = o;
}

// ---------------- log-norm ----------------
__global__ __launch_bounds__(256) void lognorm_kernel(
    const ushort* __restrict__ phk, const ushort* __restrict__ vk,
    const float* __restrict__ vb, float* __restrict__ inv) {
    int b = blockIdx.x;
    int tid = threadIdx.x;
    float p = bf16_to_f32(phk[(size_t)b * H_DIM + tid]);
    float s = -log1pf(-p);
    for (int j = tid; j < V_DIM; j += 256)
        s += bf16_to_f32(vk[(size_t)b * V_DIM + j]) * vb[j];
    for (int off = 32; off > 0; off >>= 1) s += __shfl_down(s, off, 64);
    __shared__ float wsum[4];
    int lane = tid & 63, wid = tid >> 6;
    if (lane == 0) wsum[wid] = s;
    __syncthreads();
    if (tid == 0) {
        float t = wsum[0] + wsum[1] + wsum[2] + wsum[3];
        inv[b] = expf(-t) * (1.0f / 16384.0f);
    }
}

// ---------------- transposes for gw GEMM ----------------
__global__ void build_At(const ushort* __restrict__ P, const float* __restrict__ inv,
                         float sgn, ushort* __restrict__ At) {
    __shared__ float T[64][65];
    int c = threadIdx.x & 63;
    int rb = threadIdx.x >> 6;
    int b0 = blockIdx.x * 64;
    int h0 = blockIdx.y * 64;
    for (int r = rb; r < 64; r += 4) {
        int b = b0 + r;
        T[c][r] = sgn * inv[b] * bf16_to_f32(P[(size_t)b * H_DIM + h0 + c]);
    }
    __syncthreads();
    for (int r = rb; r < 64; r += 4)
        At[(size_t)(h0 + r) * B_DIM + b0 + c] = bf16_rn(T[r][c]);
}

__global__ void build_Bt(const ushort* __restrict__ Sb, const float* __restrict__ Sf,
                         int use_f32, ushort* __restrict__ Bt) {
    __shared__ ushort T[64][65];
    int c = threadIdx.x & 63;
    int rb = threadIdx.x >> 6;
    int b0 = blockIdx.x * 64;
    int v0 = blockIdx.y * 64;
    for (int r = rb; r < 64; r += 4) {
        int b = b0 + r;
        T[c][r] = use_f32 ? bf16_rn(Sf[(size_t)b * V_DIM + v0 + c])
                          : Sb[(size_t)b * V_DIM + v0 + c];
    }
    __syncthreads();
    for (int r = rb; r < 64; r += 4)
        Bt[(size_t)(v0 + r) * B_DIM + b0 + c] = T[r][c];
}

// ---------------- g_vb / g_hb ----------------
__global__ void gvb_kernel(const ushort* __restrict__ vk, const ushort* __restrict__ vbat,
                           const float* __restrict__ inv, float* __restrict__ gvb) {
    int col = blockIdx.x * 256 + threadIdx.x;
    int b0 = blockIdx.y * 512;
    float acc = 0.0f;
    for (int r = 0; r < 512; ++r) {
        int b = b0 + r;
        acc += inv[b] * (bf16_to_f32(vk[(size_t)b * V_DIM + col]) -
                         bf16_to_f32(vbat[(size_t)b * V_DIM + col]));
    }
    atomicAdd(&gvb[col], acc);
}

__global__ void ghb_kernel(const ushort* __restrict__ phk, const ushort* __restrict__ ph0,
                           const float* __restrict__ inv, float* __restrict__ ghb) {
    int col = threadIdx.x;
    int b0 = blockIdx.x * 256;
    float acc = 0.0f;
    for (int r = 0; r < 256; ++r) {
        int b = b0 + r;
        acc += inv[b] * (bf16_to_f32(phk[(size_t)b * H_DIM + col]) -
                         bf16_to_f32(ph0[(size_t)b * H_DIM + col]));
    }
    atomicAdd(&ghb[col], acc);
}

extern "C" void kernel_launch(void* const* d_in, const int* in_sizes, int n_in,
                              void* d_out, int out_size, void* d_ws, size_t ws_size,
                              hipStream_t stream) {
    const float* batch = (const float*)d_in[0];
    const float* W = (const float*)d_in[1];
    const float* vb = (const float*)d_in[2];
    const float* hb = (const float*)d_in[3];

    char* base = (char*)d_ws;
    ushort* w_hi  = (ushort*)(base + 0);          // 512 KB
    ushort* w_lo  = (ushort*)(base + 524288);
    ushort* v_cur = (ushort*)(base + 2097152);    // 32 MB
    float*  inv   = (float*)(base + 35651584);    // 64 KB
    ushort* h_cur = (ushort*)(base + 35717120);   // 8 MB (aliased: At after loop)
    ushort* At    = h_cur;
    ushort* batch_bf = (ushort*)(base + 44105728); // 32 MB (aliased: Bt after last use)
    ushort* Bt    = batch_bf;
    ushort* ph0b  = (ushort*)(base + 77660160);   // 8 MB
    ushort* phkb  = (ushort*)(base + 86048768);   // 8 MB -> total 94437376 B

    float* gw  = (float*)d_out;
    float* gvb = gw + (size_t)H_DIM * V_DIM;
    float* ghb = gvb + V_DIM;

    hipMemsetAsync(d_out, 0, (size_t)out_size * sizeof(float), stream);

    // Partitionable threefry split of key(42): subkey[n] = threefry((0,42),(0,n)).
    uint32_t sk0[16], sk1[16];
    for (int n = 0; n < 16; ++n) threefry2x32(0u, 42u, 0u, (uint32_t)n, &sk0[n], &sk1[n]);

    wsplit_kernel<<<dim3(1024), dim3(256), 0, stream>>>(W, w_hi, w_lo);
    tobf16_kernel<<<dim3(B_DIM * V_DIM / 4 / 256), dim3(256), 0, stream>>>(batch, batch_bf);

    for (int i = 0; i < K_STEPS; ++i) {
        const ushort* vin = (i == 0) ? batch_bf : v_cur;
        if (i == 0) {
            mfma_gemm<3><<<dim3(B_DIM / 64, H_DIM / 64), dim3(256), 0, stream>>>(
                vin, w_hi, w_lo, hb, h_cur, ph0b, H_DIM, V_DIM, sk0[0], sk1[0]);
        } else {
            mfma_gemm<0><<<dim3(B_DIM / 64, H_DIM / 64), dim3(256), 0, stream>>>(
                vin, w_hi, w_lo, hb, h_cur, nullptr, H_DIM, V_DIM, sk0[2 * i], sk1[2 * i]);
        }
        vsample_kernel<<<dim3(B_DIM / 8), dim3(256), 0, stream>>>(
            h_cur, W, vb, v_cur, sk0[2 * i + 1], sk1[2 * i + 1]);
    }
    // negative phase hidden probs from vk
    mfma_gemm<1><<<dim3(B_DIM / 64, H_DIM / 64), dim3(256), 0, stream>>>(
        v_cur, w_hi, w_lo, hb, phkb, nullptr, H_DIM, V_DIM, 0u, 0u);

    lognorm_kernel<<<dim3(B_DIM), dim3(256), 0, stream>>>(phkb, v_cur, vb, inv);
    ghb_kernel<<<dim3(B_DIM / 256), dim3(256), 0, stream>>>(phkb, ph0b, inv, ghb);
    gvb_kernel<<<dim3(V_DIM / 256, B_DIM / 512), dim3(256), 0, stream>>>(v_cur, batch_bf, inv, gvb);

    // g_W positive phase
    build_At<<<dim3(B_DIM / 64, H_DIM / 64), dim3(256), 0, stream>>>(phkb, inv, 1.0f, At);
    build_Bt<<<dim3(B_DIM / 64, V_DIM / 64), dim3(256), 0, stream>>>(v_cur, nullptr, 0, Bt);
    mfma_gemm_acc<<<dim3(H_DIM / 64, V_DIM / 64, 16), dim3(256), 0, stream>>>(
        At, Bt, gw, V_DIM, B_DIM, 1024);
    // g_W negative phase
    build_At<<<dim3(B_DIM / 64, H_DIM / 64), dim3(256), 0, stream>>>(ph0b, inv, -1.0f, At);
    build_Bt<<<dim3(B_DIM / 64, V_DIM / 64), dim3(256), 0, stream>>>(nullptr, batch, 1, Bt);
    mfma_gemm_acc<<<dim3(H_DIM / 64, V_DIM / 64, 16), dim3(256), 0, stream>>>(
        At, Bt, gw, V_DIM, B_DIM, 1024);
}